// Round 4
// baseline (487.613 us; speedup 1.0000x reference)
//
#include <hip/hip_runtime.h>

#define NVOL   110592
#define PLANE  2304
#define TWO_PI 6.28318530717958647692f

__device__ __forceinline__ float dot4(float4 a, float4 b, float acc) {
    acc = fmaf(a.x, b.x, acc); acc = fmaf(a.y, b.y, acc);
    acc = fmaf(a.z, b.z, acc); acc = fmaf(a.w, b.w, acc);
    return acc;
}
__device__ __forceinline__ float dot4m(float4 a, float4 b, float acc) {  // acc -= a.b
    acc = fmaf(-a.x, b.x, acc); acc = fmaf(-a.y, b.y, acc);
    acc = fmaf(-a.z, b.z, acc); acc = fmaf(-a.w, b.w, acc);
    return acc;
}

// ---------------------------------------------------------------------------
// Generic (small) fused W+H cas transform — used for the Y/weights path only.
// ---------------------------------------------------------------------------
template<int LH, int LW>
__global__ void __launch_bounds__(192) cas_wh_kernel(const float* __restrict__ in,
                                                     float* __restrict__ out,
                                                     size_t inVol, size_t inPlane, int inRow,
                                                     size_t outVol, size_t outPlane) {
    __shared__ float cas48[48];
    __shared__ __align__(16) float casT[2304];
    __shared__ __align__(16) float tile[LH][48];
    __shared__ __align__(16) float tmp[LH * 48];
    const int tid = threadIdx.x;
    const int d = blockIdx.x, v = blockIdx.y;

    if (tid < 48) { float ang = (float)tid * (TWO_PI / 48.0f); cas48[tid] = cosf(ang) + sinf(ang); }
    __syncthreads();
    for (int idx = tid; idx < 2304; idx += 192) {
        int j = idx / 48, k = idx % 48;
        casT[idx] = cas48[(j * k) % 48];
    }
    const float* ib = in + (size_t)v * inVol + (size_t)d * inPlane;
    for (int idx = tid; idx < LH * LW; idx += 192)
        tile[idx / LW][idx % LW] = ib[(idx / LW) * inRow + (idx % LW)];
    __syncthreads();

    const float4* casT4 = reinterpret_cast<const float4*>(casT);
    float4* tmp4 = reinterpret_cast<float4*>(tmp);
    for (int o4 = tid; o4 < LH * 12; o4 += 192) {
        int h = o4 / 12, kq = o4 % 12;
        float4 acc = make_float4(0.f, 0.f, 0.f, 0.f);
        #pragma unroll 4
        for (int j = 0; j < LW; ++j) {
            float  t = tile[h][j];
            float4 c = casT4[j * 12 + kq];
            acc.x = fmaf(t, c.x, acc.x); acc.y = fmaf(t, c.y, acc.y);
            acc.z = fmaf(t, c.z, acc.z); acc.w = fmaf(t, c.w, acc.w);
        }
        tmp4[o4] = acc;
    }
    __syncthreads();
    float4* ob = reinterpret_cast<float4*>(out + (size_t)v * outVol + (size_t)d * outPlane);
    for (int o4 = tid; o4 < 576; o4 += 192) {
        int kh = o4 / 12, wq = o4 % 12;
        float4 acc = make_float4(0.f, 0.f, 0.f, 0.f);
        #pragma unroll 4
        for (int j = 0; j < LH; ++j) {
            float  c = casT[j * 48 + kh];
            float4 t = tmp4[j * 12 + wq];
            acc.x = fmaf(t.x, c, acc.x); acc.y = fmaf(t.y, c, acc.y);
            acc.z = fmaf(t.z, c, acc.z); acc.w = fmaf(t.w, c, acc.w);
        }
        ob[o4] = acc;
    }
}

// ---------------------------------------------------------------------------
// Register-tiled fused W+H cas transform, full 48x48 planes, 4 planes/block.
// ---------------------------------------------------------------------------
__global__ void __launch_bounds__(192) cas_wh48(const float* __restrict__ in,
                                                float* __restrict__ out) {
    __shared__ float cas48[48];
    __shared__ __align__(16) float casT[2304];
    __shared__ __align__(16) float buf[4][2496];
    const int tid = threadIdx.x;
    const int bx = blockIdx.x, v = blockIdx.y;

    if (tid < 48) { float ang = (float)tid * (TWO_PI / 48.0f); cas48[tid] = cosf(ang) + sinf(ang); }
    __syncthreads();
    for (int idx = tid; idx < 2304; idx += 192) {
        int j = idx / 48, k = idx % 48;
        casT[idx] = cas48[(j * k) % 48];
    }
    const float* ib = in + (size_t)v * NVOL + (size_t)(bx * 4) * PLANE;
    for (int idx = tid; idx < 2304; idx += 192) {
        int p = idx / 576, r = idx % 576, h = r / 12, q = r % 12;
        float4 t = *reinterpret_cast<const float4*>(ib + (size_t)p * PLANE + h * 48 + q * 4);
        float* dst = &buf[p][h * 49 + q * 4];
        dst[0] = t.x; dst[1] = t.y; dst[2] = t.z; dst[3] = t.w;
    }
    __syncthreads();

    const int p = tid / 48, pp = tid % 48;
    const int hg = pp >> 2, kg = pp & 3;
    float* tile = buf[p];
    const float4* casT4 = reinterpret_cast<const float4*>(casT);

    float4 acc[4][3];
    #pragma unroll
    for (int i = 0; i < 4; ++i)
        #pragma unroll
        for (int q = 0; q < 3; ++q) acc[i][q] = make_float4(0.f, 0.f, 0.f, 0.f);

    #pragma unroll 4
    for (int j = 0; j < 48; ++j) {
        float t0 = tile[(hg * 4 + 0) * 49 + j];
        float t1 = tile[(hg * 4 + 1) * 49 + j];
        float t2 = tile[(hg * 4 + 2) * 49 + j];
        float t3 = tile[(hg * 4 + 3) * 49 + j];
        float4 c[3];
        #pragma unroll
        for (int q = 0; q < 3; ++q) c[q] = casT4[j * 12 + kg * 3 + q];
        #pragma unroll
        for (int q = 0; q < 3; ++q) {
            acc[0][q].x = fmaf(t0, c[q].x, acc[0][q].x); acc[0][q].y = fmaf(t0, c[q].y, acc[0][q].y);
            acc[0][q].z = fmaf(t0, c[q].z, acc[0][q].z); acc[0][q].w = fmaf(t0, c[q].w, acc[0][q].w);
            acc[1][q].x = fmaf(t1, c[q].x, acc[1][q].x); acc[1][q].y = fmaf(t1, c[q].y, acc[1][q].y);
            acc[1][q].z = fmaf(t1, c[q].z, acc[1][q].z); acc[1][q].w = fmaf(t1, c[q].w, acc[1][q].w);
            acc[2][q].x = fmaf(t2, c[q].x, acc[2][q].x); acc[2][q].y = fmaf(t2, c[q].y, acc[2][q].y);
            acc[2][q].z = fmaf(t2, c[q].z, acc[2][q].z); acc[2][q].w = fmaf(t2, c[q].w, acc[2][q].w);
            acc[3][q].x = fmaf(t3, c[q].x, acc[3][q].x); acc[3][q].y = fmaf(t3, c[q].y, acc[3][q].y);
            acc[3][q].z = fmaf(t3, c[q].z, acc[3][q].z); acc[3][q].w = fmaf(t3, c[q].w, acc[3][q].w);
        }
    }
    __syncthreads();
    float* tmp = buf[p];
    #pragma unroll
    for (int i = 0; i < 4; ++i)
        #pragma unroll
        for (int q = 0; q < 3; ++q)
            *reinterpret_cast<float4*>(&tmp[(hg * 4 + i) * 52 + kg * 12 + q * 4]) = acc[i][q];
    __syncthreads();

    float4 acc2[4][3];
    #pragma unroll
    for (int i = 0; i < 4; ++i)
        #pragma unroll
        for (int q = 0; q < 3; ++q) acc2[i][q] = make_float4(0.f, 0.f, 0.f, 0.f);

    #pragma unroll 4
    for (int h = 0; h < 48; ++h) {
        float4 cf = casT4[h * 12 + hg];
        float cfa[4] = {cf.x, cf.y, cf.z, cf.w};
        float4 m[3];
        #pragma unroll
        for (int q = 0; q < 3; ++q) m[q] = *reinterpret_cast<const float4*>(&tmp[h * 52 + kg * 12 + q * 4]);
        #pragma unroll
        for (int i = 0; i < 4; ++i)
            #pragma unroll
            for (int q = 0; q < 3; ++q) {
                acc2[i][q].x = fmaf(cfa[i], m[q].x, acc2[i][q].x);
                acc2[i][q].y = fmaf(cfa[i], m[q].y, acc2[i][q].y);
                acc2[i][q].z = fmaf(cfa[i], m[q].z, acc2[i][q].z);
                acc2[i][q].w = fmaf(cfa[i], m[q].w, acc2[i][q].w);
            }
    }
    float4* ob = reinterpret_cast<float4*>(out + (size_t)v * NVOL + (size_t)(bx * 4 + p) * PLANE);
    #pragma unroll
    for (int i = 0; i < 4; ++i)
        #pragma unroll
        for (int q = 0; q < 3; ++q)
            ob[(hg * 4 + i) * 12 + kg * 3 + q] = acc2[i][q];
}

// ---------------------------------------------------------------------------
// Register-tiled D-transform + 4-term combine.
// ---------------------------------------------------------------------------
template<int JC>
__global__ void __launch_bounds__(192) cas_dcomb2(const float* __restrict__ in,
                                                  float* __restrict__ out,
                                                  size_t inVol, size_t inPlane, float scale) {
    __shared__ float cas48[48];
    __shared__ __align__(16) float casT[2304];
    __shared__ __align__(16) float tAB[2][JC * 52];
    __shared__ __align__(16) float S[2][48 * 52];
    const int tid = threadIdx.x;
    const int hp = blockIdx.x, v = blockIdx.y;
    const int hA = hp, hB = (48 - hp) % 48;

    if (tid < 48) { float ang = (float)tid * (TWO_PI / 48.0f); cas48[tid] = cosf(ang) + sinf(ang); }
    __syncthreads();
    for (int idx = tid; idx < 2304; idx += 192) {
        int j = idx / 48, k = idx % 48;
        casT[idx] = cas48[(j * k) % 48];
    }
    for (int idx = tid; idx < 2 * JC * 12; idx += 192) {
        int mm = idx / (JC * 12), r = idx % (JC * 12);
        int d = r / 12, q = r % 12;
        int hh = mm ? hB : hA;
        float4 t = *reinterpret_cast<const float4*>(in + (size_t)v * inVol + (size_t)d * inPlane + hh * 48 + q * 4);
        *reinterpret_cast<float4*>(&tAB[mm][d * 52 + q * 4]) = t;
    }
    __syncthreads();

    const int m = tid / 96, pth = tid % 96;
    const int k1g = pth >> 2, wg = pth & 3;
    float4 acc[2][3];
    #pragma unroll
    for (int i = 0; i < 2; ++i)
        #pragma unroll
        for (int q = 0; q < 3; ++q) acc[i][q] = make_float4(0.f, 0.f, 0.f, 0.f);

    #pragma unroll 4
    for (int d = 0; d < JC; ++d) {
        float c0 = casT[d * 48 + k1g * 2 + 0];
        float c1 = casT[d * 48 + k1g * 2 + 1];
        float4 t[3];
        #pragma unroll
        for (int q = 0; q < 3; ++q) t[q] = *reinterpret_cast<const float4*>(&tAB[m][d * 52 + wg * 12 + q * 4]);
        #pragma unroll
        for (int q = 0; q < 3; ++q) {
            acc[0][q].x = fmaf(c0, t[q].x, acc[0][q].x); acc[0][q].y = fmaf(c0, t[q].y, acc[0][q].y);
            acc[0][q].z = fmaf(c0, t[q].z, acc[0][q].z); acc[0][q].w = fmaf(c0, t[q].w, acc[0][q].w);
            acc[1][q].x = fmaf(c1, t[q].x, acc[1][q].x); acc[1][q].y = fmaf(c1, t[q].y, acc[1][q].y);
            acc[1][q].z = fmaf(c1, t[q].z, acc[1][q].z); acc[1][q].w = fmaf(c1, t[q].w, acc[1][q].w);
        }
    }
    #pragma unroll
    for (int i = 0; i < 2; ++i)
        #pragma unroll
        for (int q = 0; q < 3; ++q)
            *reinterpret_cast<float4*>(&S[m][(k1g * 2 + i) * 52 + wg * 12 + q * 4]) = acc[i][q];
    __syncthreads();

    float* ob = out + (size_t)v * (size_t)NVOL;
    for (int idx = tid; idx < 4608; idx += 192) {
        int side = (idx >= 2304);
        if (side && hA == hB) continue;
        int r = side ? idx - 2304 : idx;
        int k1 = r / 48, k3 = r % 48;
        int mk1 = (48 - k1) % 48, m3 = (48 - k3) % 48;
        float val;
        if (!side)
            val = S[0][k1 * 52 + m3] + S[1][k1 * 52 + k3] + S[0][mk1 * 52 + k3] - S[1][mk1 * 52 + m3];
        else
            val = S[1][k1 * 52 + m3] + S[0][k1 * 52 + k3] + S[1][mk1 * 52 + k3] - S[0][mk1 * 52 + m3];
        int k2 = side ? hB : hA;
        ob[k1 * PLANE + k2 * 48 + k3] = scale * val;
    }
}

// ---------------------------------------------------------------------------
// Pairwise frequency contraction v3: float4 staging, conflict-free LDS layout.
// 16 lead k's per block (k = 16*bx + kt); flip kf = NVOL - k.
// X LDS layout: [kt][iq*36 + b*4 + ir]  (c = b*16 + iq*4 + ir), row 144 fl
// Y LDS layout: [kt][iq*68 + o*4 + ir]  (c = (iq*4+ir)*16 + o), row 272 fl
// ---------------------------------------------------------------------------
__global__ void __launch_bounds__(256) zmul_kernel(const float* __restrict__ X,
                                                   const float* __restrict__ Y,
                                                   float* __restrict__ Z) {
    __shared__ __align__(16) float Xp[16 * 144], Xm[16 * 144];
    __shared__ __align__(16) float Yk[16 * 272], Yf[16 * 272];
    const int tid = threadIdx.x;
    const int k0 = blockIdx.x * 16;
    const bool blk0 = (blockIdx.x == 0);

    // ---- staging: all global loads issued up front (register-batched) ----
    float4 xl[2], xf0[2], xf1[2];
    #pragma unroll
    for (int it = 0; it < 2; ++it) {
        int task = it * 256 + tid;
        int c = task & 127, q = task >> 7;
        const float* xb = X + (size_t)c * NVOL;
        xl[it]  = *reinterpret_cast<const float4*>(xb + k0 + 4 * q);
        xf0[it] = *reinterpret_cast<const float4*>(xb + NVOL - k0 - 4 * q - 4);
        xf1[it] = *reinterpret_cast<const float4*>(xb + NVOL - k0 - 4 * q);
    }
    float4 yl[4], yg0[4], yg1[4];
    #pragma unroll
    for (int it = 0; it < 4; ++it) {
        int task = it * 256 + tid;
        int c = task & 255, q = task >> 8;
        const float* yb = Y + (size_t)c * NVOL;
        yl[it]  = *reinterpret_cast<const float4*>(yb + k0 + 4 * q);
        yg0[it] = *reinterpret_cast<const float4*>(yb + NVOL - k0 - 4 * q - 4);
        yg1[it] = *reinterpret_cast<const float4*>(yb + NVOL - k0 - 4 * q);
    }
    // ---- LDS stores ----
    #pragma unroll
    for (int it = 0; it < 2; ++it) {
        int task = it * 256 + tid;
        int c = task & 127, q = task >> 7;
        int b = c >> 4, iq = (c & 15) >> 2, ir = c & 3;
        int base = iq * 36 + b * 4 + ir;
        float a0 = xl[it].x, a1 = xl[it].y, a2 = xl[it].z, a3 = xl[it].w;
        float f0 = xf1[it].x, f1 = xf0[it].w, f2 = xf0[it].z, f3 = xf0[it].y;
        if (blk0 && q == 0) f0 = a0;          // k = 0 self-pair
        int r0 = (4 * q + 0) * 144 + base, r1 = (4 * q + 1) * 144 + base;
        int r2 = (4 * q + 2) * 144 + base, r3 = (4 * q + 3) * 144 + base;
        Xp[r0] = a0 + f0; Xm[r0] = a0 - f0;
        Xp[r1] = a1 + f1; Xm[r1] = a1 - f1;
        Xp[r2] = a2 + f2; Xm[r2] = a2 - f2;
        Xp[r3] = a3 + f3; Xm[r3] = a3 - f3;
    }
    #pragma unroll
    for (int it = 0; it < 4; ++it) {
        int task = it * 256 + tid;
        int c = task & 255, q = task >> 8;
        int i = c >> 4, o = c & 15, iq = i >> 2, ir = i & 3;
        int base = iq * 68 + o * 4 + ir;
        float a0 = yl[it].x, a1 = yl[it].y, a2 = yl[it].z, a3 = yl[it].w;
        float f0 = yg1[it].x, f1 = yg0[it].w, f2 = yg0[it].z, f3 = yg0[it].y;
        if (blk0 && q == 0) f0 = a0;
        int r0 = (4 * q + 0) * 272 + base, r1 = (4 * q + 1) * 272 + base;
        int r2 = (4 * q + 2) * 272 + base, r3 = (4 * q + 3) * 272 + base;
        Yk[r0] = a0; Yf[r0] = f0;
        Yk[r1] = a1; Yf[r1] = f1;
        Yk[r2] = a2; Yf[r2] = f2;
        Yk[r3] = a3; Yf[r3] = f3;
    }
    __syncthreads();

    // ---- compute: thread (side, tq, bb, oo); 4 k's x 2b x 2o outputs ----
    const int side = tid >> 7;
    const int r = tid & 127;
    const int tq = r >> 5, bb = (r >> 3) & 3, oo = r & 7;
    const float4* Xp4 = reinterpret_cast<const float4*>(Xp);   // t-row = 36 f4
    const float4* Xm4 = reinterpret_cast<const float4*>(Xm);
    const float4* Yk4 = reinterpret_cast<const float4*>(Yk);   // t-row = 68 f4
    const float4* Yf4 = reinterpret_cast<const float4*>(Yf);

    float acc[4][2][2] = {};
    if (side == 0) {
        #pragma unroll
        for (int tt = 0; tt < 4; ++tt) {
            const int t = tq * 4 + tt;
            #pragma unroll
            for (int iq = 0; iq < 4; ++iq) {
                float4 xp0 = Xp4[t * 36 + iq * 9 + bb];
                float4 xp1 = Xp4[t * 36 + iq * 9 + bb + 4];
                float4 xm0 = Xm4[t * 36 + iq * 9 + bb];
                float4 xm1 = Xm4[t * 36 + iq * 9 + bb + 4];
                float4 y0k = Yk4[t * 68 + iq * 17 + oo];
                float4 y1k = Yk4[t * 68 + iq * 17 + oo + 8];
                float4 y0f = Yf4[t * 68 + iq * 17 + oo];
                float4 y1f = Yf4[t * 68 + iq * 17 + oo + 8];
                acc[tt][0][0] = dot4(xm0, y0f, dot4(xp0, y0k, acc[tt][0][0]));
                acc[tt][0][1] = dot4(xm0, y1f, dot4(xp0, y1k, acc[tt][0][1]));
                acc[tt][1][0] = dot4(xm1, y0f, dot4(xp1, y0k, acc[tt][1][0]));
                acc[tt][1][1] = dot4(xm1, y1f, dot4(xp1, y1k, acc[tt][1][1]));
            }
        }
        #pragma unroll
        for (int bi = 0; bi < 2; ++bi)
            #pragma unroll
            for (int oi = 0; oi < 2; ++oi) {
                int bo = (bb + bi * 4) * 16 + (oo + oi * 8);
                float4 zv = make_float4(0.5f * acc[0][bi][oi], 0.5f * acc[1][bi][oi],
                                        0.5f * acc[2][bi][oi], 0.5f * acc[3][bi][oi]);
                *reinterpret_cast<float4*>(&Z[(size_t)bo * NVOL + k0 + tq * 4]) = zv;
            }
    } else {
        #pragma unroll
        for (int tt = 0; tt < 4; ++tt) {
            const int t = tq * 4 + tt;
            #pragma unroll
            for (int iq = 0; iq < 4; ++iq) {
                float4 xp0 = Xp4[t * 36 + iq * 9 + bb];
                float4 xp1 = Xp4[t * 36 + iq * 9 + bb + 4];
                float4 xm0 = Xm4[t * 36 + iq * 9 + bb];
                float4 xm1 = Xm4[t * 36 + iq * 9 + bb + 4];
                float4 y0k = Yk4[t * 68 + iq * 17 + oo];
                float4 y1k = Yk4[t * 68 + iq * 17 + oo + 8];
                float4 y0f = Yf4[t * 68 + iq * 17 + oo];
                float4 y1f = Yf4[t * 68 + iq * 17 + oo + 8];
                acc[tt][0][0] = dot4m(xm0, y0k, dot4(xp0, y0f, acc[tt][0][0]));
                acc[tt][0][1] = dot4m(xm0, y1k, dot4(xp0, y1f, acc[tt][0][1]));
                acc[tt][1][0] = dot4m(xm1, y0k, dot4(xp1, y0f, acc[tt][1][0]));
                acc[tt][1][1] = dot4m(xm1, y1k, dot4(xp1, y1f, acc[tt][1][1]));
            }
        }
        #pragma unroll
        for (int bi = 0; bi < 2; ++bi)
            #pragma unroll
            for (int oi = 0; oi < 2; ++oi) {
                int bo = (bb + bi * 4) * 16 + (oo + oi * 8);
                #pragma unroll
                for (int tt = 0; tt < 4; ++tt) {
                    int kk = k0 + tq * 4 + tt;
                    int ka = (kk == 0) ? 0 : NVOL - kk;
                    Z[(size_t)bo * NVOL + ka] = 0.5f * acc[tt][bi][oi];
                }
            }
    }
}

__global__ void __launch_bounds__(128) zmul_self_kernel(const float* __restrict__ X,
                                                        const float* __restrict__ Y,
                                                        float* __restrict__ Z) {
    const int bo = threadIdx.x, b = bo >> 4, o = bo & 15;
    const int k = NVOL / 2;
    float acc = 0.f;
    #pragma unroll
    for (int i = 0; i < 16; ++i)
        acc += X[(size_t)(b * 16 + i) * NVOL + k] * Y[(size_t)(i * 16 + o) * NVOL + k];
    Z[(size_t)bo * NVOL + k] = acc;
}

// ---------------------------------------------------------------------------
extern "C" void kernel_launch(void* const* d_in, const int* in_sizes, int n_in,
                              void* d_out, int out_size, void* d_ws, size_t ws_size,
                              hipStream_t stream) {
    const float* x = (const float*)d_in[0];     // [8,16,48,48,48]
    const float* w = (const float*)d_in[2];     // [16,16,12,12,12] compact corner
    float* out = (float*)d_out;                 // [8,16,48,48,48]

    float* HY  = (float*)d_ws;                  // 256*NVOL (Y DHT)
    float* XA  = HY + (size_t)256 * NVOL;       // 128*NVOL (H_X; zmul reads here)
    float* XB  = XA + (size_t)128 * NVOL;       // 128*NVOL (wh48 tmp, then Z)
    float* Ywh = XB;                            // 256*27648, dead before X wh48

    // ---- Y path ----
    cas_wh_kernel<12, 12><<<dim3(12, 256), 192, 0, stream>>>(w, Ywh, 1728, 144, 12, 27648, PLANE);
    cas_dcomb2<12><<<dim3(25, 256), 192, 0, stream>>>(Ywh, HY, 27648, PLANE, 0.5f);

    // ---- X path ----
    cas_wh48<<<dim3(12, 128), 192, 0, stream>>>(x, XB);
    cas_dcomb2<48><<<dim3(25, 128), 192, 0, stream>>>(XB, XA, NVOL, PLANE, 0.5f);

    // ---- Z contraction: X=XA, Y=HY -> Z=XB ----
    zmul_kernel<<<3456, 256, 0, stream>>>(XA, HY, XB);
    zmul_self_kernel<<<1, 128, 0, stream>>>(XA, HY, XB);

    // ---- out = DHT3(Z) / NVOL ----
    cas_wh48<<<dim3(12, 128), 192, 0, stream>>>(XB, XA);
    cas_dcomb2<48><<<dim3(25, 128), 192, 0, stream>>>(XA, out, NVOL, PLANE, 0.5f / (float)NVOL);
}